// Round 1
// baseline (151.711 us; speedup 1.0000x reference)
//
#include <hip/hip_runtime.h>

#define B_ 4
#define N_ 512
#define D_ 768
#define A_ 128

// ---------------------------------------------------------------------------
// k1: w1 = M @ W1 + b1 ; w2 = M @ W2 + b2, both pre-scaled by 2*log2(e).
// w1s layout [B*N][A]; w2t layout [B][A][N] (transposed for k2 staging).
// Block: 256 threads, 8 matrix rows staged in LDS; thread t owns output col t
// (t<128 -> W1 col t, t>=128 -> W2 col t-128). W loads coalesced per wave.
// ---------------------------------------------------------------------------
__global__ __launch_bounds__(256) void k1_proj(
    const float* __restrict__ M, const float* __restrict__ W1,
    const float* __restrict__ b1, const float* __restrict__ W2,
    const float* __restrict__ b2, float* __restrict__ w1s,
    float* __restrict__ w2t) {
  __shared__ float lm[8][D_];
  const int t = threadIdx.x;
  const int r0 = blockIdx.x * 8;  // global row index b*N+n, multiple of 8
  {
    const float4* src = (const float4*)(M + (size_t)r0 * D_);
    float4* dst = (float4*)(&lm[0][0]);
#pragma unroll
    for (int k = 0; k < 6; ++k) dst[t + k * 256] = src[t + k * 256];
  }
  __syncthreads();
  const bool isW1 = t < 128;
  const int a = isW1 ? t : (t - 128);
  const float* __restrict__ Wp = isW1 ? W1 : W2;
  const float bias = isW1 ? b1[a] : b2[a];
  float acc[8];
#pragma unroll
  for (int r = 0; r < 8; ++r) acc[r] = bias;
#pragma unroll 4
  for (int d = 0; d < D_; ++d) {
    const float w = Wp[d * A_ + a];
#pragma unroll
    for (int r = 0; r < 8; ++r) acc[r] = fmaf(lm[r][d], w, acc[r]);
  }
  const float SC = 2.8853900817779268f;  // 2*log2(e): e^{2x} = 2^{SC*x}
  const int b = r0 >> 9;
  const int n0 = r0 & (N_ - 1);
  if (isW1) {
#pragma unroll
    for (int r = 0; r < 8; ++r)
      w1s[(size_t)(r0 + r) * A_ + a] = acc[r] * SC;
  } else {
    float4 v0 = make_float4(acc[0] * SC, acc[1] * SC, acc[2] * SC, acc[3] * SC);
    float4 v1 = make_float4(acc[4] * SC, acc[5] * SC, acc[6] * SC, acc[7] * SC);
    float* dst = w2t + ((size_t)(b * A_ + a)) * N_ + n0;
    *(float4*)(dst) = v0;
    *(float4*)(dst + 4) = v1;
  }
}

// ---------------------------------------------------------------------------
// k2: scores[b,i,j] = sum_a v[a]*tanh-core, masked, fused row softmax.
// Block: 256 threads = 4 waves; wave w owns row i0+w. j-tiles of 64 staged
// as LDS [a][j] (pad 65 -> conflict-free per-lane reads). Lane `l` holds
// s[jt] for j = jt*64 + l; softmax reduced with __shfl_xor across 64 lanes.
// ---------------------------------------------------------------------------
__global__ __launch_bounds__(256) void k2_scores(
    const float* __restrict__ w1s, const float* __restrict__ w2t,
    const int* __restrict__ mask, const float* __restrict__ vw,
    float* __restrict__ attn) {
  __shared__ float l_w2t[A_][65];
  __shared__ float l_w1[4][A_];
  __shared__ float l_v[A_];
  const int t = threadIdx.x;
  const int lane = t & 63;
  const int w = t >> 6;
  const int i0 = blockIdx.x * 4;  // global row b*N+i, multiple of 4
  const int b = i0 >> 9;
  const int i = (i0 & (N_ - 1)) + w;
  if (t < A_) l_v[t] = vw[t];
  for (int k = t; k < 4 * A_; k += 256)
    ((float*)l_w1)[k] = w1s[(size_t)i0 * A_ + k];

  float s[8];
  for (int jt = 0; jt < 8; ++jt) {
    __syncthreads();  // protect prev tile (and initial w1/v staging)
    const int j0 = jt * 64;
    const float* src = w2t + (size_t)b * A_ * N_ + j0;
#pragma unroll
    for (int k = 0; k < 8; ++k) {
      int f = t + k * 256;       // float4 index within [128 a][16 f4]
      int aa = f >> 4;
      int j4 = (f & 15) * 4;
      float4 val = *(const float4*)(src + (size_t)aa * N_ + j4);
      l_w2t[aa][j4 + 0] = val.x;
      l_w2t[aa][j4 + 1] = val.y;
      l_w2t[aa][j4 + 2] = val.z;
      l_w2t[aa][j4 + 3] = val.w;
    }
    __syncthreads();
    float acc = 0.f;
#pragma unroll 4
    for (int a = 0; a < A_; ++a) {
      float x = l_w1[w][a] + l_w2t[a][lane];  // already scaled by 2*log2e
      x = fminf(x, 30.f);                     // avoid inf/inf -> NaN
      float e = __builtin_amdgcn_exp2f(x);    // e^{2x}
      acc = fmaf(l_v[a], (e - 1.f) * __builtin_amdgcn_rcpf(e + 1.f), acc);
    }
    int m = mask[((size_t)(b * N_ + i)) * N_ + j0 + lane];
    s[jt] = m ? acc : -3.402823466e38f;  // np.finfo(f32).min, NOT -inf
  }
  // fused softmax over the 512-wide row (8 regs x 64 lanes)
  float rmax = s[0];
#pragma unroll
  for (int jt = 1; jt < 8; ++jt) rmax = fmaxf(rmax, s[jt]);
#pragma unroll
  for (int off = 32; off > 0; off >>= 1)
    rmax = fmaxf(rmax, __shfl_xor(rmax, off));
  const float L2E = 1.4426950408889634f;
  float rsum = 0.f;
#pragma unroll
  for (int jt = 0; jt < 8; ++jt) {
    // all-masked row: s-rmax = 0 -> exp 1 -> uniform 1/512 (matches ref)
    s[jt] = __builtin_amdgcn_exp2f((s[jt] - rmax) * L2E);
    rsum += s[jt];
  }
#pragma unroll
  for (int off = 32; off > 0; off >>= 1) rsum += __shfl_xor(rsum, off);
  const float inv = __builtin_amdgcn_rcpf(rsum);
  float* dst = attn + ((size_t)(b * N_ + i)) * N_ + lane;
#pragma unroll
  for (int jt = 0; jt < 8; ++jt) dst[jt * 64] = s[jt] * inv;
}

// ---------------------------------------------------------------------------
// k3: out[b] = attn[b] @ M[b].  64x64 C-tile per 256-thread block, TJ=32.
// attn tile stored transposed [jj][ii] so both fragments are float4 reads.
// Thread (tx,ty) computes C[ty*4..+3][tx*4..+3].
// ---------------------------------------------------------------------------
__global__ __launch_bounds__(256) void k3_av(
    const float* __restrict__ attn, const float* __restrict__ M,
    float* __restrict__ out) {
  __shared__ float l_at[32][68];  // [jj][ii], pad 68 keeps float4 alignment
  __shared__ float l_m[32][68];   // [jj][dd]
  const int t = threadIdx.x;
  const int tx = t & 15;
  const int ty = t >> 4;
  const int d0 = blockIdx.x * 64;
  const int i0 = blockIdx.y * 64;
  const int b = blockIdx.z;
  float acc[4][4];
#pragma unroll
  for (int r = 0; r < 4; ++r)
#pragma unroll
    for (int c = 0; c < 4; ++c) acc[r][c] = 0.f;

  for (int j0 = 0; j0 < N_; j0 += 32) {
    __syncthreads();
#pragma unroll
    for (int k = 0; k < 2; ++k) {  // attn tile, transposed store
      int f = t + k * 256;
      int ii = f >> 3;
      int j4 = (f & 7) * 4;
      const float4 val = *(const float4*)(attn +
          ((size_t)(b * N_ + i0 + ii)) * N_ + j0 + j4);
      l_at[j4 + 0][ii] = val.x;
      l_at[j4 + 1][ii] = val.y;
      l_at[j4 + 2][ii] = val.z;
      l_at[j4 + 3][ii] = val.w;
    }
#pragma unroll
    for (int k = 0; k < 2; ++k) {  // matrix tile, linear store
      int f = t + k * 256;
      int jj = f >> 4;
      int dd4 = (f & 15) * 4;
      *(float4*)(&l_m[jj][dd4]) = *(const float4*)(M +
          ((size_t)(b * N_ + j0 + jj)) * D_ + d0 + dd4);
    }
    __syncthreads();
#pragma unroll 8
    for (int jj = 0; jj < 32; ++jj) {
      const float4 av = *(const float4*)(&l_at[jj][ty * 4]);
      const float4 bv = *(const float4*)(&l_m[jj][tx * 4]);
      const float ar[4] = {av.x, av.y, av.z, av.w};
      const float br[4] = {bv.x, bv.y, bv.z, bv.w};
#pragma unroll
      for (int r = 0; r < 4; ++r)
#pragma unroll
        for (int c = 0; c < 4; ++c) acc[r][c] = fmaf(ar[r], br[c], acc[r][c]);
    }
  }
#pragma unroll
  for (int r = 0; r < 4; ++r) {
    float4 o = make_float4(acc[r][0], acc[r][1], acc[r][2], acc[r][3]);
    *(float4*)(out + ((size_t)(b * N_ + i0 + ty * 4 + r)) * D_ + d0 + tx * 4) = o;
  }
}

extern "C" void kernel_launch(void* const* d_in, const int* in_sizes, int n_in,
                              void* d_out, int out_size, void* d_ws,
                              size_t ws_size, hipStream_t stream) {
  const float* M = (const float*)d_in[0];
  const int* mask = (const int*)d_in[1];
  const float* W1 = (const float*)d_in[2];
  const float* b1 = (const float*)d_in[3];
  const float* W2 = (const float*)d_in[4];
  const float* b2 = (const float*)d_in[5];
  const float* vw = (const float*)d_in[6];
  float* out = (float*)d_out;

  float* w1s = (float*)d_ws;             // [B*N][A]      1 MB
  float* w2t = w1s + B_ * N_ * A_;       // [B][A][N]     1 MB
  float* attn = w2t + B_ * A_ * N_;      // [B*N][N]      4 MB

  k1_proj<<<(B_ * N_) / 8, 256, 0, stream>>>(M, W1, b1, W2, b2, w1s, w2t);
  k2_scores<<<(B_ * N_) / 4, 256, 0, stream>>>(w1s, w2t, mask, vw, attn);
  k3_av<<<dim3(D_ / 64, N_ / 64, B_), 256, 0, stream>>>(attn, M, out);
}

// Round 2
// 116.900 us; speedup vs baseline: 1.2978x; 1.2978x over previous
//
#include <hip/hip_runtime.h>

#define B_ 4
#define N_ 512
#define D_ 768
#define A_ 128

// ---------------------------------------------------------------------------
// k1 v2: C[2048][256] = M[2048][768] @ [W1|W2][768][256], + bias, *2log2(e).
// Proper tiled GEMM: 32 rows x 64 cols per 256-thread block, Ktile=32,
// double-buffered LDS with register prefetch (1 sync/iter). Micro-tile 2x4.
// Col-tiles 0,1 -> W1 (written row-major to w1s); 2,3 -> W2 (transposed via
// LDS in the epilogue to w2t[B][A][N], keeping k2's layout unchanged).
// ---------------------------------------------------------------------------
__global__ __launch_bounds__(256) void k1_proj(
    const float* __restrict__ M, const float* __restrict__ W1,
    const float* __restrict__ b1, const float* __restrict__ W2,
    const float* __restrict__ b2, float* __restrict__ w1s,
    float* __restrict__ w2t) {
  __shared__ __align__(16) union SM {
    struct { float a[2][32][34]; float b[2][32][68]; } g;  // GEMM buffers
    float tr[64][36];                                      // epilogue transpose
  } sm;
  const int t = threadIdx.x;
  const int tx = t & 15;   // col group (4 cols)
  const int ty = t >> 4;   // row group (2 rows)
  const int x = blockIdx.x;            // 0..3 col tile
  const int row0 = blockIdx.y * 32;    // global row (b*N+n), 32 | 512
  const bool isW1 = x < 2;
  const float* __restrict__ Wp = isW1 ? W1 : W2;
  const int cbase = (x & 1) * 64;      // col offset within the 128-wide half

  // staging thread mapping
  const int ai = t >> 3;          // 0..31: M row within tile
  const int ak = (t & 7) * 4;     // k offset (float4)
  const int wk = t >> 4;          // 0..15: W k-row (and +16)
  const int wc = (t & 15) * 4;    // W col offset (float4)

  // prologue: prefetch + stage K-tile 0
  float4 mA = *(const float4*)(M + (size_t)(row0 + ai) * D_ + ak);
  float4 wB0 = *(const float4*)(Wp + (size_t)wk * A_ + cbase + wc);
  float4 wB1 = *(const float4*)(Wp + (size_t)(wk + 16) * A_ + cbase + wc);
  sm.g.a[0][ak + 0][ai] = mA.x;
  sm.g.a[0][ak + 1][ai] = mA.y;
  sm.g.a[0][ak + 2][ai] = mA.z;
  sm.g.a[0][ak + 3][ai] = mA.w;
  *(float4*)(&sm.g.b[0][wk][wc]) = wB0;
  *(float4*)(&sm.g.b[0][wk + 16][wc]) = wB1;
  __syncthreads();

  float acc[2][4];
#pragma unroll
  for (int r = 0; r < 2; ++r)
#pragma unroll
    for (int c = 0; c < 4; ++c) acc[r][c] = 0.f;

  const int NKT = D_ / 32;  // 24
  for (int kt = 0; kt < NKT; ++kt) {
    const int cur = kt & 1;
    if (kt + 1 < NKT) {  // prefetch next K-tile into registers
      const int k0 = (kt + 1) * 32;
      mA = *(const float4*)(M + (size_t)(row0 + ai) * D_ + k0 + ak);
      wB0 = *(const float4*)(Wp + (size_t)(k0 + wk) * A_ + cbase + wc);
      wB1 = *(const float4*)(Wp + (size_t)(k0 + wk + 16) * A_ + cbase + wc);
    }
#pragma unroll
    for (int kk = 0; kk < 32; ++kk) {
      const float2 av = *(const float2*)(&sm.g.a[cur][kk][ty * 2]);
      const float4 bv = *(const float4*)(&sm.g.b[cur][kk][tx * 4]);
      acc[0][0] = fmaf(av.x, bv.x, acc[0][0]);
      acc[0][1] = fmaf(av.x, bv.y, acc[0][1]);
      acc[0][2] = fmaf(av.x, bv.z, acc[0][2]);
      acc[0][3] = fmaf(av.x, bv.w, acc[0][3]);
      acc[1][0] = fmaf(av.y, bv.x, acc[1][0]);
      acc[1][1] = fmaf(av.y, bv.y, acc[1][1]);
      acc[1][2] = fmaf(av.y, bv.z, acc[1][2]);
      acc[1][3] = fmaf(av.y, bv.w, acc[1][3]);
    }
    if (kt + 1 < NKT) {  // write prefetched tile to the other buffer
      const int nxt = cur ^ 1;
      sm.g.a[nxt][ak + 0][ai] = mA.x;
      sm.g.a[nxt][ak + 1][ai] = mA.y;
      sm.g.a[nxt][ak + 2][ai] = mA.z;
      sm.g.a[nxt][ak + 3][ai] = mA.w;
      *(float4*)(&sm.g.b[nxt][wk][wc]) = wB0;
      *(float4*)(&sm.g.b[nxt][wk + 16][wc]) = wB1;
    }
    __syncthreads();
  }

  // epilogue: bias + scale by 2*log2(e)
  const float SC = 2.8853900817779268f;  // e^{2x} = 2^{SC*x}
  const float* bp = isW1 ? b1 : b2;
#pragma unroll
  for (int c = 0; c < 4; ++c) {
    const float bias = bp[cbase + tx * 4 + c];
#pragma unroll
    for (int r = 0; r < 2; ++r) acc[r][c] = (acc[r][c] + bias) * SC;
  }

  if (isW1) {
    float* dst = w1s + (size_t)(row0 + ty * 2) * A_ + cbase + tx * 4;
    *(float4*)(dst) = make_float4(acc[0][0], acc[0][1], acc[0][2], acc[0][3]);
    *(float4*)(dst + A_) = make_float4(acc[1][0], acc[1][1], acc[1][2], acc[1][3]);
  } else {
    // transpose 32n x 64c tile via LDS -> w2t[b][a][n]
    // (last loop iter ended in __syncthreads, safe to reuse sm)
#pragma unroll
    for (int c = 0; c < 4; ++c) {
#pragma unroll
      for (int r = 0; r < 2; ++r)
        sm.tr[tx * 4 + c][ty * 2 + r] = acc[r][c];
    }
    __syncthreads();
    const int b = row0 >> 9;
    const int n0 = row0 & (N_ - 1);
#pragma unroll
    for (int s = 0; s < 2; ++s) {
      const int f = t + s * 256;      // 512 float4s: 64 c x 8 n4-groups
      const int c = f >> 3;
      const int n4 = (f & 7) * 4;
      float4 o = *(const float4*)(&sm.tr[c][n4]);
      *(float4*)(w2t + ((size_t)(b * A_ + cbase + c)) * N_ + n0 + n4) = o;
    }
  }
}

// ---------------------------------------------------------------------------
// k2: scores[b,i,j] = sum_a v[a]*tanh-core, masked, fused row softmax.
// Block: 256 threads = 4 waves; wave w owns row i0+w. j-tiles of 64 staged
// as LDS [a][j] (pad 65 -> conflict-free per-lane reads). Lane `l` holds
// s[jt] for j = jt*64 + l; softmax reduced with __shfl_xor across 64 lanes.
// ---------------------------------------------------------------------------
__global__ __launch_bounds__(256) void k2_scores(
    const float* __restrict__ w1s, const float* __restrict__ w2t,
    const int* __restrict__ mask, const float* __restrict__ vw,
    float* __restrict__ attn) {
  __shared__ float l_w2t[A_][65];
  __shared__ float l_w1[4][A_];
  __shared__ float l_v[A_];
  const int t = threadIdx.x;
  const int lane = t & 63;
  const int w = t >> 6;
  const int i0 = blockIdx.x * 4;  // global row b*N+i, multiple of 4
  const int b = i0 >> 9;
  const int i = (i0 & (N_ - 1)) + w;
  if (t < A_) l_v[t] = vw[t];
  for (int k = t; k < 4 * A_; k += 256)
    ((float*)l_w1)[k] = w1s[(size_t)i0 * A_ + k];

  float s[8];
  for (int jt = 0; jt < 8; ++jt) {
    __syncthreads();  // protect prev tile (and initial w1/v staging)
    const int j0 = jt * 64;
    const float* src = w2t + (size_t)b * A_ * N_ + j0;
#pragma unroll
    for (int k = 0; k < 8; ++k) {
      int f = t + k * 256;       // float4 index within [128 a][16 f4]
      int aa = f >> 4;
      int j4 = (f & 15) * 4;
      float4 val = *(const float4*)(src + (size_t)aa * N_ + j4);
      l_w2t[aa][j4 + 0] = val.x;
      l_w2t[aa][j4 + 1] = val.y;
      l_w2t[aa][j4 + 2] = val.z;
      l_w2t[aa][j4 + 3] = val.w;
    }
    __syncthreads();
    float acc = 0.f;
#pragma unroll 4
    for (int a = 0; a < A_; ++a) {
      float x = l_w1[w][a] + l_w2t[a][lane];  // already scaled by 2*log2e
      x = fminf(x, 30.f);                     // avoid inf/inf -> NaN
      float e = __builtin_amdgcn_exp2f(x);    // e^{2x}
      acc = fmaf(l_v[a], (e - 1.f) * __builtin_amdgcn_rcpf(e + 1.f), acc);
    }
    int m = mask[((size_t)(b * N_ + i)) * N_ + j0 + lane];
    s[jt] = m ? acc : -3.402823466e38f;  // np.finfo(f32).min, NOT -inf
  }
  // fused softmax over the 512-wide row (8 regs x 64 lanes)
  float rmax = s[0];
#pragma unroll
  for (int jt = 1; jt < 8; ++jt) rmax = fmaxf(rmax, s[jt]);
#pragma unroll
  for (int off = 32; off > 0; off >>= 1)
    rmax = fmaxf(rmax, __shfl_xor(rmax, off));
  const float L2E = 1.4426950408889634f;
  float rsum = 0.f;
#pragma unroll
  for (int jt = 0; jt < 8; ++jt) {
    // all-masked row: s-rmax = 0 -> exp 1 -> uniform 1/512 (matches ref)
    s[jt] = __builtin_amdgcn_exp2f((s[jt] - rmax) * L2E);
    rsum += s[jt];
  }
#pragma unroll
  for (int off = 32; off > 0; off >>= 1) rsum += __shfl_xor(rsum, off);
  const float inv = __builtin_amdgcn_rcpf(rsum);
  float* dst = attn + ((size_t)(b * N_ + i)) * N_ + lane;
#pragma unroll
  for (int jt = 0; jt < 8; ++jt) dst[jt * 64] = s[jt] * inv;
}

// ---------------------------------------------------------------------------
// k3: out[b] = attn[b] @ M[b].  64x64 C-tile per 256-thread block, TJ=32.
// attn tile stored transposed [jj][ii] so both fragments are float4 reads.
// Thread (tx,ty) computes C[ty*4..+3][tx*4..+3].
// ---------------------------------------------------------------------------
__global__ __launch_bounds__(256) void k3_av(
    const float* __restrict__ attn, const float* __restrict__ M,
    float* __restrict__ out) {
  __shared__ float l_at[32][68];  // [jj][ii], pad 68 keeps float4 alignment
  __shared__ float l_m[32][68];   // [jj][dd]
  const int t = threadIdx.x;
  const int tx = t & 15;
  const int ty = t >> 4;
  const int d0 = blockIdx.x * 64;
  const int i0 = blockIdx.y * 64;
  const int b = blockIdx.z;
  float acc[4][4];
#pragma unroll
  for (int r = 0; r < 4; ++r)
#pragma unroll
    for (int c = 0; c < 4; ++c) acc[r][c] = 0.f;

  for (int j0 = 0; j0 < N_; j0 += 32) {
    __syncthreads();
#pragma unroll
    for (int k = 0; k < 2; ++k) {  // attn tile, transposed store
      int f = t + k * 256;
      int ii = f >> 3;
      int j4 = (f & 7) * 4;
      const float4 val = *(const float4*)(attn +
          ((size_t)(b * N_ + i0 + ii)) * N_ + j0 + j4);
      l_at[j4 + 0][ii] = val.x;
      l_at[j4 + 1][ii] = val.y;
      l_at[j4 + 2][ii] = val.z;
      l_at[j4 + 3][ii] = val.w;
    }
#pragma unroll
    for (int k = 0; k < 2; ++k) {  // matrix tile, linear store
      int f = t + k * 256;
      int jj = f >> 4;
      int dd4 = (f & 15) * 4;
      *(float4*)(&l_m[jj][dd4]) = *(const float4*)(M +
          ((size_t)(b * N_ + j0 + jj)) * D_ + d0 + dd4);
    }
    __syncthreads();
#pragma unroll 8
    for (int jj = 0; jj < 32; ++jj) {
      const float4 av = *(const float4*)(&l_at[jj][ty * 4]);
      const float4 bv = *(const float4*)(&l_m[jj][tx * 4]);
      const float ar[4] = {av.x, av.y, av.z, av.w};
      const float br[4] = {bv.x, bv.y, bv.z, bv.w};
#pragma unroll
      for (int r = 0; r < 4; ++r)
#pragma unroll
        for (int c = 0; c < 4; ++c) acc[r][c] = fmaf(ar[r], br[c], acc[r][c]);
    }
  }
#pragma unroll
  for (int r = 0; r < 4; ++r) {
    float4 o = make_float4(acc[r][0], acc[r][1], acc[r][2], acc[r][3]);
    *(float4*)(out + ((size_t)(b * N_ + i0 + ty * 4 + r)) * D_ + d0 + tx * 4) = o;
  }
}

extern "C" void kernel_launch(void* const* d_in, const int* in_sizes, int n_in,
                              void* d_out, int out_size, void* d_ws,
                              size_t ws_size, hipStream_t stream) {
  const float* M = (const float*)d_in[0];
  const int* mask = (const int*)d_in[1];
  const float* W1 = (const float*)d_in[2];
  const float* b1 = (const float*)d_in[3];
  const float* W2 = (const float*)d_in[4];
  const float* b2 = (const float*)d_in[5];
  const float* vw = (const float*)d_in[6];
  float* out = (float*)d_out;

  float* w1s = (float*)d_ws;             // [B*N][A]      1 MB
  float* w2t = w1s + B_ * N_ * A_;       // [B][A][N]     1 MB
  float* attn = w2t + B_ * A_ * N_;      // [B*N][N]      4 MB

  k1_proj<<<dim3(4, (B_ * N_) / 32), 256, 0, stream>>>(M, W1, b1, W2, b2, w1s, w2t);
  k2_scores<<<(B_ * N_) / 4, 256, 0, stream>>>(w1s, w2t, mask, vw, attn);
  k3_av<<<dim3(D_ / 64, N_ / 64, B_), 256, 0, stream>>>(attn, M, out);
}

// Round 3
// 97.542 us; speedup vs baseline: 1.5553x; 1.1985x over previous
//
#include <hip/hip_runtime.h>

#define B_ 4
#define N_ 512
#define D_ 768
#define A_ 128

// ---------------------------------------------------------------------------
// k1: C[2048][256] = M[2048][768] @ [W1|W2][768][256], + bias, *2log2(e).
// Tiled GEMM: 32 rows x 64 cols per 256-thread block, Ktile=32, double-
// buffered LDS with register prefetch. Micro-tile 2x4.
// Col-tiles 0,1 -> W1 (row-major to w1s[row][A]); 2,3 -> W2 written float4-
// interleaved to w2p[b][A/4][N][4] (f4 index (b*32+c)*N+j holds a=4c..4c+3)
// so k2's w2 reads are lane-coalesced.
// ---------------------------------------------------------------------------
__global__ __launch_bounds__(256) void k1_proj(
    const float* __restrict__ M, const float* __restrict__ W1,
    const float* __restrict__ b1, const float* __restrict__ W2,
    const float* __restrict__ b2, float* __restrict__ w1s,
    float* __restrict__ w2p) {
  __shared__ __align__(16) float sa[2][32][34];
  __shared__ __align__(16) float sb[2][32][68];
  const int t = threadIdx.x;
  const int tx = t & 15;   // col group (4 cols)
  const int ty = t >> 4;   // row group (2 rows)
  const int x = blockIdx.x;            // 0..3 col tile
  const int row0 = blockIdx.y * 32;    // global row (b*N+n)
  const bool isW1 = x < 2;
  const float* __restrict__ Wp = isW1 ? W1 : W2;
  const int cbase = (x & 1) * 64;      // col offset within the 128-wide half

  const int ai = t >> 3;          // 0..31: M row within tile
  const int ak = (t & 7) * 4;     // k offset (float4)
  const int wk = t >> 4;          // 0..15: W k-row (and +16)
  const int wc = (t & 15) * 4;    // W col offset (float4)

  float4 mA = *(const float4*)(M + (size_t)(row0 + ai) * D_ + ak);
  float4 wB0 = *(const float4*)(Wp + (size_t)wk * A_ + cbase + wc);
  float4 wB1 = *(const float4*)(Wp + (size_t)(wk + 16) * A_ + cbase + wc);
  sa[0][ak + 0][ai] = mA.x;
  sa[0][ak + 1][ai] = mA.y;
  sa[0][ak + 2][ai] = mA.z;
  sa[0][ak + 3][ai] = mA.w;
  *(float4*)(&sb[0][wk][wc]) = wB0;
  *(float4*)(&sb[0][wk + 16][wc]) = wB1;
  __syncthreads();

  float acc[2][4];
#pragma unroll
  for (int r = 0; r < 2; ++r)
#pragma unroll
    for (int c = 0; c < 4; ++c) acc[r][c] = 0.f;

  const int NKT = D_ / 32;  // 24
  for (int kt = 0; kt < NKT; ++kt) {
    const int cur = kt & 1;
    if (kt + 1 < NKT) {
      const int k0 = (kt + 1) * 32;
      mA = *(const float4*)(M + (size_t)(row0 + ai) * D_ + k0 + ak);
      wB0 = *(const float4*)(Wp + (size_t)(k0 + wk) * A_ + cbase + wc);
      wB1 = *(const float4*)(Wp + (size_t)(k0 + wk + 16) * A_ + cbase + wc);
    }
#pragma unroll
    for (int kk = 0; kk < 32; ++kk) {
      const float2 av = *(const float2*)(&sa[cur][kk][ty * 2]);
      const float4 bv = *(const float4*)(&sb[cur][kk][tx * 4]);
      acc[0][0] = fmaf(av.x, bv.x, acc[0][0]);
      acc[0][1] = fmaf(av.x, bv.y, acc[0][1]);
      acc[0][2] = fmaf(av.x, bv.z, acc[0][2]);
      acc[0][3] = fmaf(av.x, bv.w, acc[0][3]);
      acc[1][0] = fmaf(av.y, bv.x, acc[1][0]);
      acc[1][1] = fmaf(av.y, bv.y, acc[1][1]);
      acc[1][2] = fmaf(av.y, bv.z, acc[1][2]);
      acc[1][3] = fmaf(av.y, bv.w, acc[1][3]);
    }
    if (kt + 1 < NKT) {
      const int nxt = cur ^ 1;
      sa[nxt][ak + 0][ai] = mA.x;
      sa[nxt][ak + 1][ai] = mA.y;
      sa[nxt][ak + 2][ai] = mA.z;
      sa[nxt][ak + 3][ai] = mA.w;
      *(float4*)(&sb[nxt][wk][wc]) = wB0;
      *(float4*)(&sb[nxt][wk + 16][wc]) = wB1;
    }
    __syncthreads();
  }

  const float SC = 2.8853900817779268f;  // 2*log2(e): e^{2x} = 2^{SC*x}
  const float* bp = isW1 ? b1 : b2;
#pragma unroll
  for (int c = 0; c < 4; ++c) {
    const float bias = bp[cbase + tx * 4 + c];
#pragma unroll
    for (int r = 0; r < 2; ++r) acc[r][c] = (acc[r][c] + bias) * SC;
  }

  if (isW1) {
    float* dst = w1s + (size_t)(row0 + ty * 2) * A_ + cbase + tx * 4;
    *(float4*)(dst) = make_float4(acc[0][0], acc[0][1], acc[0][2], acc[0][3]);
    *(float4*)(dst + A_) = make_float4(acc[1][0], acc[1][1], acc[1][2], acc[1][3]);
  } else {
    const int b = row0 >> 9;
    const int n0 = row0 & (N_ - 1);
    const int c = (x & 1) * 16 + tx;  // a-chunk 0..31
    float4* dst = (float4*)w2p + ((size_t)(b * 32 + c)) * N_ + n0 + ty * 2;
    dst[0] = make_float4(acc[0][0], acc[0][1], acc[0][2], acc[0][3]);
    dst[1] = make_float4(acc[1][0], acc[1][1], acc[1][2], acc[1][3]);
  }
}

// ---------------------------------------------------------------------------
// k2 v3: score(i,j) = Vsum - sum_a 2v[a]/(exp2(w1s+w2)+1), masked, fused
// row softmax. Block = 256 thr = 4 waves: wave (r,h) = row i0+r, j-half h.
// Per wave: 4 j-batches of 64 (lane=j) accumulated simultaneously; w2 read
// as coalesced float4 from w2p; w1/-2v broadcast from LDS. Cross-half
// softmax merge via tiny LDS reductions.
// ---------------------------------------------------------------------------
__global__ __launch_bounds__(256) void k2_scores(
    const float* __restrict__ w1s, const float* __restrict__ w2p,
    const int* __restrict__ mask, const float* __restrict__ vw,
    float* __restrict__ attn) {
  __shared__ float l_w1[2 * A_];
  __shared__ float l_v2[A_];
  __shared__ float l_red[2][2];
  __shared__ float l_sum[2][2];
  const int t = threadIdx.x;
  const int lane = t & 63;
  const int w = t >> 6;
  const int r = w >> 1;   // row within block
  const int h = w & 1;    // j-half
  const int i0 = blockIdx.x * 2;  // global row b*N+i
  const int b = i0 >> 9;
  const int i = i0 + r;

  l_w1[t] = w1s[(size_t)i0 * A_ + t];
  if (t < A_) l_v2[t] = -2.f * vw[t];
  // Vsum (per wave, redundant)
  float vs = vw[lane] + vw[64 + lane];
#pragma unroll
  for (int off = 32; off; off >>= 1) vs += __shfl_xor(vs, off);
  __syncthreads();

  const int jbase = h * 256 + lane;
  int m0 = mask[(size_t)i * N_ + jbase];
  int m1 = mask[(size_t)i * N_ + jbase + 64];
  int m2 = mask[(size_t)i * N_ + jbase + 128];
  int m3 = mask[(size_t)i * N_ + jbase + 192];

  float acc0 = vs, acc1 = vs, acc2 = vs, acc3 = vs;
  const float4* __restrict__ w2q =
      (const float4*)w2p + (size_t)b * 32 * N_ + jbase;
  const float4* __restrict__ w1q = (const float4*)&l_w1[r * A_];
  const float4* __restrict__ v2q = (const float4*)&l_v2[0];

#define K2_COMP(xx, accv)                                                   \
  {                                                                         \
    float e0 = __builtin_amdgcn_exp2f(wa.x + xx.x);                         \
    accv = fmaf(vv.x, __builtin_amdgcn_rcpf(e0 + 1.f), accv);               \
    float e1 = __builtin_amdgcn_exp2f(wa.y + xx.y);                         \
    accv = fmaf(vv.y, __builtin_amdgcn_rcpf(e1 + 1.f), accv);               \
    float e2 = __builtin_amdgcn_exp2f(wa.z + xx.z);                         \
    accv = fmaf(vv.z, __builtin_amdgcn_rcpf(e2 + 1.f), accv);               \
    float e3 = __builtin_amdgcn_exp2f(wa.w + xx.w);                         \
    accv = fmaf(vv.w, __builtin_amdgcn_rcpf(e3 + 1.f), accv);               \
  }

#pragma unroll 2
  for (int c = 0; c < 32; ++c) {
    const float4 wa = w1q[c];
    const float4 vv = v2q[c];
    const float4 x0 = w2q[(size_t)c * N_];
    const float4 x1 = w2q[(size_t)c * N_ + 64];
    const float4 x2 = w2q[(size_t)c * N_ + 128];
    const float4 x3 = w2q[(size_t)c * N_ + 192];
    K2_COMP(x0, acc0)
    K2_COMP(x1, acc1)
    K2_COMP(x2, acc2)
    K2_COMP(x3, acc3)
  }
#undef K2_COMP

  const float NEG = -3.402823466e38f;  // np.finfo(f32).min
  float s0 = m0 ? acc0 : NEG;
  float s1 = m1 ? acc1 : NEG;
  float s2 = m2 ? acc2 : NEG;
  float s3 = m3 ? acc3 : NEG;

  // wave max then cross-half max
  float rmax = fmaxf(fmaxf(s0, s1), fmaxf(s2, s3));
#pragma unroll
  for (int off = 32; off; off >>= 1) rmax = fmaxf(rmax, __shfl_xor(rmax, off));
  if (lane == 0) l_red[r][h] = rmax;
  __syncthreads();
  rmax = fmaxf(l_red[r][0], l_red[r][1]);

  const float L2E = 1.4426950408889634f;
  // all-masked row: s-rmax = 0 -> exp 1 -> uniform 1/512 (matches ref)
  float p0 = __builtin_amdgcn_exp2f((s0 - rmax) * L2E);
  float p1 = __builtin_amdgcn_exp2f((s1 - rmax) * L2E);
  float p2 = __builtin_amdgcn_exp2f((s2 - rmax) * L2E);
  float p3 = __builtin_amdgcn_exp2f((s3 - rmax) * L2E);
  float psum = (p0 + p1) + (p2 + p3);
#pragma unroll
  for (int off = 32; off; off >>= 1) psum += __shfl_xor(psum, off);
  if (lane == 0) l_sum[r][h] = psum;
  __syncthreads();
  const float inv = __builtin_amdgcn_rcpf(l_sum[r][0] + l_sum[r][1]);

  float* dst = attn + (size_t)i * N_ + jbase;
  dst[0] = p0 * inv;
  dst[64] = p1 * inv;
  dst[128] = p2 * inv;
  dst[192] = p3 * inv;
}

// ---------------------------------------------------------------------------
// k3: out[b] = attn[b] @ M[b].  64x64 C-tile per 256-thread block, TJ=32.
// ---------------------------------------------------------------------------
__global__ __launch_bounds__(256) void k3_av(
    const float* __restrict__ attn, const float* __restrict__ M,
    float* __restrict__ out) {
  __shared__ float l_at[32][68];  // [jj][ii]
  __shared__ float l_m[32][68];   // [jj][dd]
  const int t = threadIdx.x;
  const int tx = t & 15;
  const int ty = t >> 4;
  const int d0 = blockIdx.x * 64;
  const int i0 = blockIdx.y * 64;
  const int b = blockIdx.z;
  float acc[4][4];
#pragma unroll
  for (int r = 0; r < 4; ++r)
#pragma unroll
    for (int c = 0; c < 4; ++c) acc[r][c] = 0.f;

  for (int j0 = 0; j0 < N_; j0 += 32) {
    __syncthreads();
#pragma unroll
    for (int k = 0; k < 2; ++k) {
      int f = t + k * 256;
      int ii = f >> 3;
      int j4 = (f & 7) * 4;
      const float4 val = *(const float4*)(attn +
          ((size_t)(b * N_ + i0 + ii)) * N_ + j0 + j4);
      l_at[j4 + 0][ii] = val.x;
      l_at[j4 + 1][ii] = val.y;
      l_at[j4 + 2][ii] = val.z;
      l_at[j4 + 3][ii] = val.w;
    }
#pragma unroll
    for (int k = 0; k < 2; ++k) {
      int f = t + k * 256;
      int jj = f >> 4;
      int dd4 = (f & 15) * 4;
      *(float4*)(&l_m[jj][dd4]) = *(const float4*)(M +
          ((size_t)(b * N_ + j0 + jj)) * D_ + d0 + dd4);
    }
    __syncthreads();
#pragma unroll 8
    for (int jj = 0; jj < 32; ++jj) {
      const float4 av = *(const float4*)(&l_at[jj][ty * 4]);
      const float4 bv = *(const float4*)(&l_m[jj][tx * 4]);
      const float ar[4] = {av.x, av.y, av.z, av.w};
      const float br[4] = {bv.x, bv.y, bv.z, bv.w};
#pragma unroll
      for (int r = 0; r < 4; ++r)
#pragma unroll
        for (int c = 0; c < 4; ++c) acc[r][c] = fmaf(ar[r], br[c], acc[r][c]);
    }
  }
#pragma unroll
  for (int r = 0; r < 4; ++r) {
    float4 o = make_float4(acc[r][0], acc[r][1], acc[r][2], acc[r][3]);
    *(float4*)(out + ((size_t)(b * N_ + i0 + ty * 4 + r)) * D_ + d0 + tx * 4) = o;
  }
}

extern "C" void kernel_launch(void* const* d_in, const int* in_sizes, int n_in,
                              void* d_out, int out_size, void* d_ws,
                              size_t ws_size, hipStream_t stream) {
  const float* M = (const float*)d_in[0];
  const int* mask = (const int*)d_in[1];
  const float* W1 = (const float*)d_in[2];
  const float* b1 = (const float*)d_in[3];
  const float* W2 = (const float*)d_in[4];
  const float* b2 = (const float*)d_in[5];
  const float* vw = (const float*)d_in[6];
  float* out = (float*)d_out;

  float* w1s = (float*)d_ws;             // [B*N][A]          1 MB
  float* w2p = w1s + B_ * N_ * A_;       // [B][A/4][N][4]    1 MB
  float* attn = w2p + B_ * A_ * N_;      // [B*N][N]          4 MB

  k1_proj<<<dim3(4, (B_ * N_) / 32), 256, 0, stream>>>(M, W1, b1, W2, b2, w1s, w2p);
  k2_scores<<<(B_ * N_) / 2, 256, 0, stream>>>(w1s, w2p, mask, vw, attn);
  k3_av<<<dim3(D_ / 64, N_ / 64, B_), 256, 0, stream>>>(attn, M, out);
}

// Round 4
// 90.845 us; speedup vs baseline: 1.6700x; 1.0737x over previous
//
#include <hip/hip_runtime.h>

#define B_ 4
#define N_ 512
#define D_ 768
#define A_ 128

typedef short bf16x8 __attribute__((ext_vector_type(8)));
typedef ushort u16x8 __attribute__((ext_vector_type(8)));
typedef float f32x4 __attribute__((ext_vector_type(4)));

__device__ __forceinline__ ushort f2h(float x) {  // f32 -> bf16 bits, RNE
  uint u = __builtin_bit_cast(uint, x);
  return (ushort)((u + 0x7fffu + ((u >> 16) & 1u)) >> 16);
}
__device__ __forceinline__ float h2f(ushort h) {
  uint u = ((uint)h) << 16;
  return __builtin_bit_cast(float, u);
}
__device__ __forceinline__ bf16x8 ld8(const ushort* p) {
  return *(const bf16x8*)p;
}
#define MFMA(a, b, c) __builtin_amdgcn_mfma_f32_16x16x32_bf16(a, b, c, 0, 0, 0)

// ---------------------------------------------------------------------------
// k0m: split M (f32) into bf16 hi/lo, in TWO layouts:
//  Mr_h/Mr_l: [2048][768] row-major   (k1's A operand: K=d contiguous)
//  Mt_h/Mt_l: [4][768][512] transposed (k3's B operand: K=j contiguous)
// Block: 256 thr, tile = 32 n x 64 d; transpose via LDS (row pad 40 -> 16B
// aligned u16x8 reads).
// ---------------------------------------------------------------------------
__global__ __launch_bounds__(256) void k0m(
    const float* __restrict__ M, ushort* __restrict__ Mr_h,
    ushort* __restrict__ Mr_l, ushort* __restrict__ Mt_h,
    ushort* __restrict__ Mt_l) {
  __shared__ ushort lds_h[64][40];
  __shared__ ushort lds_l[64][40];
  const int t = threadIdx.x;
  const int d0 = blockIdx.x * 64;
  const int n0 = blockIdx.y * 32;
  const int b = blockIdx.z;
  const int n = t >> 3;          // 0..31
  const int dg = (t & 7) * 8;    // 0..56
  const size_t roff = ((size_t)(b * N_ + n0 + n)) * D_ + d0 + dg;
  const float4 v0 = *(const float4*)(M + roff);
  const float4 v1 = *(const float4*)(M + roff + 4);
  const float x[8] = {v0.x, v0.y, v0.z, v0.w, v1.x, v1.y, v1.z, v1.w};
  u16x8 vh, vl;
#pragma unroll
  for (int e = 0; e < 8; ++e) {
    ushort h = f2h(x[e]);
    ushort l = f2h(x[e] - h2f(h));
    vh[e] = h;
    vl[e] = l;
    lds_h[dg + e][n] = h;
    lds_l[dg + e][n] = l;
  }
  *(u16x8*)(Mr_h + roff) = vh;
  *(u16x8*)(Mr_l + roff) = vl;
  __syncthreads();
  const int dd = t >> 2;          // 0..63
  const int ng = (t & 3) * 8;     // 0..24
  const size_t toff = ((size_t)b * D_ + d0 + dd) * N_ + n0 + ng;
  *(u16x8*)(Mt_h + toff) = *(const u16x8*)(&lds_h[dd][ng]);
  *(u16x8*)(Mt_l + toff) = *(const u16x8*)(&lds_l[dd][ng]);
}

// ---------------------------------------------------------------------------
// k0w: Wt[c][k] = (c<128 ? W1[k][c] : W2[k][c-128]), bf16 hi/lo, [256][768].
// Block = 256 thr (thread = col c), blockIdx.x = k-group of 8.
// ---------------------------------------------------------------------------
__global__ __launch_bounds__(256) void k0w(
    const float* __restrict__ W1, const float* __restrict__ W2,
    ushort* __restrict__ Wt_h, ushort* __restrict__ Wt_l) {
  const int c = threadIdx.x;
  const int k0 = blockIdx.x * 8;
  const float* __restrict__ Wp = (c < A_) ? W1 : W2;
  const int cc = c & (A_ - 1);
  u16x8 vh, vl;
#pragma unroll
  for (int e = 0; e < 8; ++e) {
    float x = Wp[(size_t)(k0 + e) * A_ + cc];
    ushort h = f2h(x);
    vh[e] = h;
    vl[e] = f2h(x - h2f(h));
  }
  *(u16x8*)(Wt_h + (size_t)c * D_ + k0) = vh;
  *(u16x8*)(Wt_l + (size_t)c * D_ + k0) = vl;
}

// ---------------------------------------------------------------------------
// k1: [w1|w2][2048][256] = M @ [W1|W2], +bias, *2log2(e).  MFMA 16x16x32
// bf16, error-compensated 3-pass (Ah@Bh + Ah@Bl + Al@Bh ~ f32 accuracy).
// 1 wave/block, wave tile 32 rows x 64 cols, zero LDS (direct global frags).
// cols 0-127 -> w1s[row][128]; 128-255 -> w2p[b][32][512][4] f4-interleaved.
// ---------------------------------------------------------------------------
__global__ __launch_bounds__(64) void k1_mfma(
    const ushort* __restrict__ Mr_h, const ushort* __restrict__ Mr_l,
    const ushort* __restrict__ Wt_h, const ushort* __restrict__ Wt_l,
    const float* __restrict__ b1, const float* __restrict__ b2,
    float* __restrict__ w1s, float* __restrict__ w2p) {
  const int l = threadIdx.x;
  const int r = l & 15, g = l >> 4;
  const int row0 = blockIdx.x * 32;
  const int cb = blockIdx.y * 64;
  f32x4 acc[2][4] = {};
  for (int k0 = 0; k0 < D_; k0 += 32) {
    bf16x8 a_h[2], a_l[2], b_h[4], b_l[4];
#pragma unroll
    for (int fi = 0; fi < 2; ++fi) {
      const size_t off = (size_t)(row0 + fi * 16 + r) * D_ + k0 + g * 8;
      a_h[fi] = ld8(Mr_h + off);
      a_l[fi] = ld8(Mr_l + off);
    }
#pragma unroll
    for (int fj = 0; fj < 4; ++fj) {
      const size_t off = (size_t)(cb + fj * 16 + r) * D_ + k0 + g * 8;
      b_h[fj] = ld8(Wt_h + off);
      b_l[fj] = ld8(Wt_l + off);
    }
#pragma unroll
    for (int fi = 0; fi < 2; ++fi)
#pragma unroll
      for (int fj = 0; fj < 4; ++fj) {
        acc[fi][fj] = MFMA(a_h[fi], b_h[fj], acc[fi][fj]);
        acc[fi][fj] = MFMA(a_h[fi], b_l[fj], acc[fi][fj]);
        acc[fi][fj] = MFMA(a_l[fi], b_h[fj], acc[fi][fj]);
      }
  }
  const float SC = 2.8853900817779268f;  // 2*log2(e): e^{2x} = 2^{SC*x}
#pragma unroll
  for (int fj = 0; fj < 4; ++fj) {
    const int c = cb + fj * 16 + r;
    const float bias = (c < A_) ? b1[c] : b2[c - A_];
#pragma unroll
    for (int fi = 0; fi < 2; ++fi)
#pragma unroll
      for (int rr = 0; rr < 4; ++rr) {
        const int row = row0 + fi * 16 + g * 4 + rr;
        const float v = (acc[fi][fj][rr] + bias) * SC;
        if (c < A_) {
          w1s[(size_t)row * A_ + c] = v;
        } else {
          const int b = row >> 9, n = row & (N_ - 1), cc = c - A_;
          w2p[(((size_t)(b * 32 + (cc >> 2)) * N_) + n) * 4 + (cc & 3)] = v;
        }
      }
  }
}

// ---------------------------------------------------------------------------
// k2: score(i,j) = Vsum - sum_a 2v[a]/(exp2(w1s+w2)+1), masked, fused row
// softmax; writes attn as bf16 hi/lo split (k3's A operand).
// Block = 4 waves: wave (r,h) = row i0+r, j-half h; 4 j-batches per lane.
// ---------------------------------------------------------------------------
__global__ __launch_bounds__(256) void k2_scores(
    const float* __restrict__ w1s, const float* __restrict__ w2p,
    const int* __restrict__ mask, const float* __restrict__ vw,
    ushort* __restrict__ ah, ushort* __restrict__ al) {
  __shared__ float l_w1[2 * A_];
  __shared__ float l_v2[A_];
  __shared__ float l_red[2][2];
  __shared__ float l_sum[2][2];
  const int t = threadIdx.x;
  const int lane = t & 63;
  const int w = t >> 6;
  const int r = w >> 1;
  const int h = w & 1;
  const int i0 = blockIdx.x * 2;
  const int b = i0 >> 9;
  const int i = i0 + r;

  l_w1[t] = w1s[(size_t)i0 * A_ + t];
  if (t < A_) l_v2[t] = -2.f * vw[t];
  float vs = vw[lane] + vw[64 + lane];
#pragma unroll
  for (int off = 32; off; off >>= 1) vs += __shfl_xor(vs, off);
  __syncthreads();

  const int jbase = h * 256 + lane;
  const int m0 = mask[(size_t)i * N_ + jbase];
  const int m1 = mask[(size_t)i * N_ + jbase + 64];
  const int m2 = mask[(size_t)i * N_ + jbase + 128];
  const int m3 = mask[(size_t)i * N_ + jbase + 192];

  float acc0 = vs, acc1 = vs, acc2 = vs, acc3 = vs;
  const float4* __restrict__ w2q =
      (const float4*)w2p + (size_t)b * 32 * N_ + jbase;
  const float4* __restrict__ w1q = (const float4*)&l_w1[r * A_];
  const float4* __restrict__ v2q = (const float4*)&l_v2[0];

#define K2_COMP(xx, accv)                                                   \
  {                                                                         \
    float e0 = __builtin_amdgcn_exp2f(wa.x + xx.x);                         \
    accv = fmaf(vv.x, __builtin_amdgcn_rcpf(e0 + 1.f), accv);               \
    float e1 = __builtin_amdgcn_exp2f(wa.y + xx.y);                         \
    accv = fmaf(vv.y, __builtin_amdgcn_rcpf(e1 + 1.f), accv);               \
    float e2 = __builtin_amdgcn_exp2f(wa.z + xx.z);                         \
    accv = fmaf(vv.z, __builtin_amdgcn_rcpf(e2 + 1.f), accv);               \
    float e3 = __builtin_amdgcn_exp2f(wa.w + xx.w);                         \
    accv = fmaf(vv.w, __builtin_amdgcn_rcpf(e3 + 1.f), accv);               \
  }

#pragma unroll 2
  for (int c = 0; c < 32; ++c) {
    const float4 wa = w1q[c];
    const float4 vv = v2q[c];
    const float4 x0 = w2q[(size_t)c * N_];
    const float4 x1 = w2q[(size_t)c * N_ + 64];
    const float4 x2 = w2q[(size_t)c * N_ + 128];
    const float4 x3 = w2q[(size_t)c * N_ + 192];
    K2_COMP(x0, acc0)
    K2_COMP(x1, acc1)
    K2_COMP(x2, acc2)
    K2_COMP(x3, acc3)
  }
#undef K2_COMP

  const float NEG = -3.402823466e38f;  // np.finfo(f32).min
  float s0 = m0 ? acc0 : NEG;
  float s1 = m1 ? acc1 : NEG;
  float s2 = m2 ? acc2 : NEG;
  float s3 = m3 ? acc3 : NEG;

  float rmax = fmaxf(fmaxf(s0, s1), fmaxf(s2, s3));
#pragma unroll
  for (int off = 32; off; off >>= 1) rmax = fmaxf(rmax, __shfl_xor(rmax, off));
  if (lane == 0) l_red[r][h] = rmax;
  __syncthreads();
  rmax = fmaxf(l_red[r][0], l_red[r][1]);

  const float L2E = 1.4426950408889634f;
  // all-masked row: s-rmax = 0 -> exp 1 -> uniform 1/512 (matches ref)
  float p0 = __builtin_amdgcn_exp2f((s0 - rmax) * L2E);
  float p1 = __builtin_amdgcn_exp2f((s1 - rmax) * L2E);
  float p2 = __builtin_amdgcn_exp2f((s2 - rmax) * L2E);
  float p3 = __builtin_amdgcn_exp2f((s3 - rmax) * L2E);
  float psum = (p0 + p1) + (p2 + p3);
#pragma unroll
  for (int off = 32; off; off >>= 1) psum += __shfl_xor(psum, off);
  if (lane == 0) l_sum[r][h] = psum;
  __syncthreads();
  const float inv = __builtin_amdgcn_rcpf(l_sum[r][0] + l_sum[r][1]);

  const size_t base = (size_t)i * N_ + jbase;
  const float q[4] = {p0 * inv, p1 * inv, p2 * inv, p3 * inv};
#pragma unroll
  for (int e = 0; e < 4; ++e) {
    const ushort hh = f2h(q[e]);
    ah[base + e * 64] = hh;
    al[base + e * 64] = f2h(q[e] - h2f(hh));
  }
}

// ---------------------------------------------------------------------------
// k3: out[b] = attn[b] @ M[b].  MFMA 16x16x32 bf16, 3-pass split, zero LDS.
// 1 wave/block, wave tile 32 i x 64 d. A from ah/al [row][512], B from
// Mt_h/Mt_l [b][768][512].
// ---------------------------------------------------------------------------
__global__ __launch_bounds__(64) void k3_mfma(
    const ushort* __restrict__ ah, const ushort* __restrict__ al,
    const ushort* __restrict__ Mt_h, const ushort* __restrict__ Mt_l,
    float* __restrict__ out) {
  const int l = threadIdx.x;
  const int r = l & 15, g = l >> 4;
  const int row0 = blockIdx.x * 32;    // global row b*N+i
  const int d0 = blockIdx.y * 64;
  const int b = row0 >> 9;
  const ushort* __restrict__ Bh = Mt_h + (size_t)b * D_ * N_;
  const ushort* __restrict__ Bl = Mt_l + (size_t)b * D_ * N_;
  f32x4 acc[2][4] = {};
  for (int j0 = 0; j0 < N_; j0 += 32) {
    bf16x8 a_h[2], a_l[2], b_h[4], b_l[4];
#pragma unroll
    for (int fi = 0; fi < 2; ++fi) {
      const size_t off = (size_t)(row0 + fi * 16 + r) * N_ + j0 + g * 8;
      a_h[fi] = ld8(ah + off);
      a_l[fi] = ld8(al + off);
    }
#pragma unroll
    for (int fd = 0; fd < 4; ++fd) {
      const size_t off = (size_t)(d0 + fd * 16 + r) * N_ + j0 + g * 8;
      b_h[fd] = ld8(Bh + off);
      b_l[fd] = ld8(Bl + off);
    }
#pragma unroll
    for (int fi = 0; fi < 2; ++fi)
#pragma unroll
      for (int fd = 0; fd < 4; ++fd) {
        acc[fi][fd] = MFMA(a_h[fi], b_h[fd], acc[fi][fd]);
        acc[fi][fd] = MFMA(a_h[fi], b_l[fd], acc[fi][fd]);
        acc[fi][fd] = MFMA(a_l[fi], b_h[fd], acc[fi][fd]);
      }
  }
#pragma unroll
  for (int fi = 0; fi < 2; ++fi)
#pragma unroll
    for (int fd = 0; fd < 4; ++fd)
#pragma unroll
      for (int rr = 0; rr < 4; ++rr)
        out[(size_t)(row0 + fi * 16 + g * 4 + rr) * D_ + d0 + fd * 16 + r] =
            acc[fi][fd][rr];
}

extern "C" void kernel_launch(void* const* d_in, const int* in_sizes, int n_in,
                              void* d_out, int out_size, void* d_ws,
                              size_t ws_size, hipStream_t stream) {
  const float* M = (const float*)d_in[0];
  const int* mask = (const int*)d_in[1];
  const float* W1 = (const float*)d_in[2];
  const float* b1 = (const float*)d_in[3];
  const float* W2 = (const float*)d_in[4];
  const float* b2 = (const float*)d_in[5];
  const float* vw = (const float*)d_in[6];
  float* out = (float*)d_out;

  // workspace carve-up: 18.75 MB total
  float* w1s = (float*)d_ws;                      // [2048][128] f32   1 MB
  float* w2p = w1s + 2048 * A_;                   // [4][32][512][4]   1 MB
  ushort* ah = (ushort*)(w2p + 4 * 32 * N_ * 4);  // [2048][512] bf16  2 MB
  ushort* al = ah + 2048 * N_;                    //                   2 MB
  ushort* Mr_h = al + 2048 * N_;                  // [2048][768] bf16  3 MB
  ushort* Mr_l = Mr_h + 2048 * D_;                //                   3 MB
  ushort* Mt_h = Mr_l + 2048 * D_;                // [4][768][512]     3 MB
  ushort* Mt_l = Mt_h + 2048 * D_;                //                   3 MB
  ushort* Wt_h = Mt_l + 2048 * D_;                // [256][768] bf16   .375
  ushort* Wt_l = Wt_h + 256 * D_;                 //                   .375

  k0m<<<dim3(D_ / 64, N_ / 32, B_), 256, 0, stream>>>(M, Mr_h, Mr_l, Mt_h, Mt_l);
  k0w<<<D_ / 8, 256, 0, stream>>>(W1, W2, Wt_h, Wt_l);
  k1_mfma<<<dim3(2048 / 32, 4), 64, 0, stream>>>(Mr_h, Mr_l, Wt_h, Wt_l,
                                                 b1, b2, w1s, w2p);
  k2_scores<<<(B_ * N_) / 2, 256, 0, stream>>>(w1s, w2p, mask, vw, ah, al);
  k3_mfma<<<dim3(2048 / 32, D_ / 64), 64, 0, stream>>>(ah, al, Mt_h, Mt_l, out);
}

// Round 5
// 84.344 us; speedup vs baseline: 1.7987x; 1.0771x over previous
//
#include <hip/hip_runtime.h>

#define B_ 4
#define N_ 512
#define D_ 768
#define A_ 128

typedef short bf16x8 __attribute__((ext_vector_type(8)));
typedef ushort u16x8 __attribute__((ext_vector_type(8)));
typedef float f32x4 __attribute__((ext_vector_type(4)));

__device__ __forceinline__ ushort f2h(float x) {  // f32 -> bf16 bits, RNE
  uint u = __builtin_bit_cast(uint, x);
  return (ushort)((u + 0x7fffu + ((u >> 16) & 1u)) >> 16);
}
__device__ __forceinline__ float h2f(ushort h) {
  uint u = ((uint)h) << 16;
  return __builtin_bit_cast(float, u);
}
__device__ __forceinline__ bf16x8 ld8(const ushort* p) {
  return *(const bf16x8*)p;
}
#define MFMA(a, b, c) __builtin_amdgcn_mfma_f32_16x16x32_bf16(a, b, c, 0, 0, 0)

// ---------------------------------------------------------------------------
// k0m: split M (f32) into bf16 hi/lo, in TWO layouts:
//  Mr_h/Mr_l: [2048][768] row-major   (k1's A operand: K=d contiguous)
//  Mt_h/Mt_l: [4][768][512] transposed (k3's B operand: K=j contiguous)
// ---------------------------------------------------------------------------
__global__ __launch_bounds__(256) void k0m(
    const float* __restrict__ M, ushort* __restrict__ Mr_h,
    ushort* __restrict__ Mr_l, ushort* __restrict__ Mt_h,
    ushort* __restrict__ Mt_l) {
  __shared__ ushort lds_h[64][40];
  __shared__ ushort lds_l[64][40];
  const int t = threadIdx.x;
  const int d0 = blockIdx.x * 64;
  const int n0 = blockIdx.y * 32;
  const int b = blockIdx.z;
  const int n = t >> 3;          // 0..31
  const int dg = (t & 7) * 8;    // 0..56
  const size_t roff = ((size_t)(b * N_ + n0 + n)) * D_ + d0 + dg;
  const float4 v0 = *(const float4*)(M + roff);
  const float4 v1 = *(const float4*)(M + roff + 4);
  const float x[8] = {v0.x, v0.y, v0.z, v0.w, v1.x, v1.y, v1.z, v1.w};
  u16x8 vh, vl;
#pragma unroll
  for (int e = 0; e < 8; ++e) {
    ushort h = f2h(x[e]);
    ushort l = f2h(x[e] - h2f(h));
    vh[e] = h;
    vl[e] = l;
    lds_h[dg + e][n] = h;
    lds_l[dg + e][n] = l;
  }
  *(u16x8*)(Mr_h + roff) = vh;
  *(u16x8*)(Mr_l + roff) = vl;
  __syncthreads();
  const int dd = t >> 2;          // 0..63
  const int ng = (t & 3) * 8;     // 0..24
  const size_t toff = ((size_t)b * D_ + d0 + dd) * N_ + n0 + ng;
  *(u16x8*)(Mt_h + toff) = *(const u16x8*)(&lds_h[dd][ng]);
  *(u16x8*)(Mt_l + toff) = *(const u16x8*)(&lds_l[dd][ng]);
}

// ---------------------------------------------------------------------------
// k0w: Wt[c][k] = (c<128 ? W1[k][c] : W2[k][c-128]), bf16 hi/lo, [256][768].
// ---------------------------------------------------------------------------
__global__ __launch_bounds__(256) void k0w(
    const float* __restrict__ W1, const float* __restrict__ W2,
    ushort* __restrict__ Wt_h, ushort* __restrict__ Wt_l) {
  const int c = threadIdx.x;
  const int k0 = blockIdx.x * 8;
  const float* __restrict__ Wp = (c < A_) ? W1 : W2;
  const int cc = c & (A_ - 1);
  u16x8 vh, vl;
#pragma unroll
  for (int e = 0; e < 8; ++e) {
    float x = Wp[(size_t)(k0 + e) * A_ + cc];
    ushort h = f2h(x);
    vh[e] = h;
    vl[e] = f2h(x - h2f(h));
  }
  *(u16x8*)(Wt_h + (size_t)c * D_ + k0) = vh;
  *(u16x8*)(Wt_l + (size_t)c * D_ + k0) = vl;
}

// ---------------------------------------------------------------------------
// k1: [w1|w2][2048][256] = M @ [W1|W2], +bias, *2log2(e).  MFMA 16x16x32
// bf16, 3-pass split (Ah@Bh + Ah@Bl + Al@Bh). 1 wave/block, tile 32x32
// (512 blocks -> 2 waves/CU for latency hiding), zero LDS.
// cols 0-127 -> w1s[row][128]; 128-255 -> w2p[b][32][512][4] f4-interleaved.
// ---------------------------------------------------------------------------
__global__ __launch_bounds__(64) void k1_mfma(
    const ushort* __restrict__ Mr_h, const ushort* __restrict__ Mr_l,
    const ushort* __restrict__ Wt_h, const ushort* __restrict__ Wt_l,
    const float* __restrict__ b1, const float* __restrict__ b2,
    float* __restrict__ w1s, float* __restrict__ w2p) {
  const int l = threadIdx.x;
  const int r = l & 15, g = l >> 4;
  const int row0 = blockIdx.x * 32;
  const int cb = blockIdx.y * 32;
  const bool isW1 = cb < A_;
  f32x4 acc[2][2] = {};
  for (int k0 = 0; k0 < D_; k0 += 32) {
    bf16x8 a_h[2], a_l[2], b_h[2], b_l[2];
#pragma unroll
    for (int fi = 0; fi < 2; ++fi) {
      const size_t off = (size_t)(row0 + fi * 16 + r) * D_ + k0 + g * 8;
      a_h[fi] = ld8(Mr_h + off);
      a_l[fi] = ld8(Mr_l + off);
    }
#pragma unroll
    for (int fj = 0; fj < 2; ++fj) {
      const size_t off = (size_t)(cb + fj * 16 + r) * D_ + k0 + g * 8;
      b_h[fj] = ld8(Wt_h + off);
      b_l[fj] = ld8(Wt_l + off);
    }
#pragma unroll
    for (int fi = 0; fi < 2; ++fi)
#pragma unroll
      for (int fj = 0; fj < 2; ++fj) {
        acc[fi][fj] = MFMA(a_h[fi], b_h[fj], acc[fi][fj]);
        acc[fi][fj] = MFMA(a_h[fi], b_l[fj], acc[fi][fj]);
        acc[fi][fj] = MFMA(a_l[fi], b_h[fj], acc[fi][fj]);
      }
  }
  const float SC = 2.8853900817779268f;  // 2*log2(e): e^{2x} = 2^{SC*x}
#pragma unroll
  for (int fj = 0; fj < 2; ++fj) {
    const int c = cb + fj * 16 + r;
    const float bias = isW1 ? b1[c] : b2[c - A_];
#pragma unroll
    for (int fi = 0; fi < 2; ++fi)
#pragma unroll
      for (int rr = 0; rr < 4; ++rr) {
        const int row = row0 + fi * 16 + g * 4 + rr;
        const float v = (acc[fi][fj][rr] + bias) * SC;
        if (isW1) {
          w1s[(size_t)row * A_ + c] = v;
        } else {
          const int b = row >> 9, n = row & (N_ - 1), cc = c - A_;
          w2p[(((size_t)(b * 32 + (cc >> 2)) * N_) + n) * 4 + (cc & 3)] = v;
        }
      }
  }
}

// ---------------------------------------------------------------------------
// k2 v4: mask-compacted additive scores + fused softmax.
// 1 wave = 1 row. Ballot/popcount builds compact unmasked-j list in LDS;
// score = Vsum - sum_a 2v[a]*rcp(exp2(w1+w2)+1) computed ONLY for compact j
// (w2 via 16B float4 gather from w2p). Scores scatter to per-row LDS buf
// (zero-init => masked stay exactly 0 after softmax, matching ref's
// underflowed exp(f32.min - rmax)). exp2 only on compact entries; final
// coalesced u16x8 bf16 hi/lo write. cnt==0 row -> exact 1/512.
// ---------------------------------------------------------------------------
__global__ __launch_bounds__(256) void k2_scores(
    const float* __restrict__ w1s, const float* __restrict__ w2p,
    const int* __restrict__ mask, const float* __restrict__ vw,
    ushort* __restrict__ ah, ushort* __restrict__ al) {
  __shared__ float l_w1[4][A_];
  __shared__ float l_v2[A_];
  __shared__ float p_lds[4][N_];
  __shared__ ushort jl[4][N_];
  const int t = threadIdx.x;
  const int lane = t & 63;
  const int w = t >> 6;
  const int i0 = blockIdx.x * 4;
  const int b = i0 >> 9;
  const int i = i0 + w;

  for (int k = t; k < 4 * A_; k += 256)
    ((float*)l_w1)[k] = w1s[(size_t)i0 * A_ + k];
  if (t < A_) l_v2[t] = -2.f * vw[t];
  for (int k = t; k < 4 * N_; k += 256) ((float*)p_lds)[k] = 0.f;
  float vs = vw[lane] + vw[64 + lane];
#pragma unroll
  for (int off = 32; off; off >>= 1) vs += __shfl_xor(vs, off);
  __syncthreads();

  // --- compaction: list of unmasked j for row i ---
  int cnt = 0;
#pragma unroll
  for (int e = 0; e < 8; ++e) {
    const int m = mask[(size_t)i * N_ + e * 64 + lane];
    const unsigned long long bal = __ballot(m != 0);
    if (m) {
      const int rank = __popcll(bal & ((1ull << lane) - 1ull));
      jl[w][cnt + rank] = (ushort)(e * 64 + lane);
    }
    cnt += __popcll(bal);
  }

  const float4* __restrict__ w2q =
      (const float4*)w2p + (size_t)b * 32 * N_;
  const float4* __restrict__ w1q = (const float4*)&l_w1[w][0];
  const float4* __restrict__ v2q = (const float4*)&l_v2[0];
  const int np = (cnt + 63) >> 6;

  // --- pass 1: scores -> p_lds scatter, track max ---
  float smax = -3.402823466e38f;
  for (int ch = 0; ch < np; ++ch) {
    const int idx = ch * 64 + lane;
    const bool val = idx < cnt;
    const int j = jl[w][val ? idx : 0];
    float a0 = vs;
#pragma unroll 4
    for (int c = 0; c < 32; ++c) {
      const float4 wa = w1q[c];
      const float4 vv = v2q[c];
      const float4 x = w2q[(size_t)c * N_ + j];
      const float e0 = __builtin_amdgcn_exp2f(wa.x + x.x);
      const float e1 = __builtin_amdgcn_exp2f(wa.y + x.y);
      const float e2 = __builtin_amdgcn_exp2f(wa.z + x.z);
      const float e3 = __builtin_amdgcn_exp2f(wa.w + x.w);
      a0 = fmaf(vv.x, __builtin_amdgcn_rcpf(e0 + 1.f), a0);
      a0 = fmaf(vv.y, __builtin_amdgcn_rcpf(e1 + 1.f), a0);
      a0 = fmaf(vv.z, __builtin_amdgcn_rcpf(e2 + 1.f), a0);
      a0 = fmaf(vv.w, __builtin_amdgcn_rcpf(e3 + 1.f), a0);
    }
    if (val) {
      p_lds[w][j] = a0;
      smax = fmaxf(smax, a0);
    }
  }
#pragma unroll
  for (int off = 32; off; off >>= 1) smax = fmaxf(smax, __shfl_xor(smax, off));

  // --- pass 2: exp on compact entries + sum ---
  const float L2E = 1.4426950408889634f;
  float psum = 0.f;
  for (int ch = 0; ch < np; ++ch) {
    const int idx = ch * 64 + lane;
    const bool val = idx < cnt;
    const int j = jl[w][val ? idx : 0];
    const float p = __builtin_amdgcn_exp2f((p_lds[w][j] - smax) * L2E);
    if (val) {
      p_lds[w][j] = p;
      psum += p;
    }
  }
#pragma unroll
  for (int off = 32; off; off >>= 1) psum += __shfl_xor(psum, off);
  const float inv = __builtin_amdgcn_rcpf(psum);

  // --- final coalesced bf16 hi/lo write ---
  u16x8 vh, vl;
  if (cnt == 0) {
#pragma unroll
    for (int e = 0; e < 8; ++e) {  // exact 1/512 (all-masked row, ref match)
      vh[e] = 0x3B00;
      vl[e] = 0;
    }
  } else {
    const float4 q0 = *(const float4*)&p_lds[w][lane * 8];
    const float4 q1 = *(const float4*)&p_lds[w][lane * 8 + 4];
    const float q[8] = {q0.x, q0.y, q0.z, q0.w, q1.x, q1.y, q1.z, q1.w};
#pragma unroll
    for (int e = 0; e < 8; ++e) {
      const float pv = q[e] * inv;
      const ushort hh = f2h(pv);
      vh[e] = hh;
      vl[e] = f2h(pv - h2f(hh));
    }
  }
  *(u16x8*)(ah + (size_t)i * N_ + lane * 8) = vh;
  *(u16x8*)(al + (size_t)i * N_ + lane * 8) = vl;
}

// ---------------------------------------------------------------------------
// k3: out[b] = attn[b] @ M[b].  MFMA 16x16x32 bf16, 3-pass split, zero LDS.
// 1 wave/block, tile 32 i x 32 d (1536 blocks -> 6 waves/CU).
// ---------------------------------------------------------------------------
__global__ __launch_bounds__(64) void k3_mfma(
    const ushort* __restrict__ ah, const ushort* __restrict__ al,
    const ushort* __restrict__ Mt_h, const ushort* __restrict__ Mt_l,
    float* __restrict__ out) {
  const int l = threadIdx.x;
  const int r = l & 15, g = l >> 4;
  const int row0 = blockIdx.x * 32;    // global row b*N+i
  const int d0 = blockIdx.y * 32;
  const int b = row0 >> 9;
  const ushort* __restrict__ Bh = Mt_h + (size_t)b * D_ * N_;
  const ushort* __restrict__ Bl = Mt_l + (size_t)b * D_ * N_;
  f32x4 acc[2][2] = {};
  for (int j0 = 0; j0 < N_; j0 += 32) {
    bf16x8 a_h[2], a_l[2], b_h[2], b_l[2];
#pragma unroll
    for (int fi = 0; fi < 2; ++fi) {
      const size_t off = (size_t)(row0 + fi * 16 + r) * N_ + j0 + g * 8;
      a_h[fi] = ld8(ah + off);
      a_l[fi] = ld8(al + off);
    }
#pragma unroll
    for (int fd = 0; fd < 2; ++fd) {
      const size_t off = (size_t)(d0 + fd * 16 + r) * N_ + j0 + g * 8;
      b_h[fd] = ld8(Bh + off);
      b_l[fd] = ld8(Bl + off);
    }
#pragma unroll
    for (int fi = 0; fi < 2; ++fi)
#pragma unroll
      for (int fd = 0; fd < 2; ++fd) {
        acc[fi][fd] = MFMA(a_h[fi], b_h[fd], acc[fi][fd]);
        acc[fi][fd] = MFMA(a_h[fi], b_l[fd], acc[fi][fd]);
        acc[fi][fd] = MFMA(a_l[fi], b_h[fd], acc[fi][fd]);
      }
  }
#pragma unroll
  for (int fi = 0; fi < 2; ++fi)
#pragma unroll
    for (int fd = 0; fd < 2; ++fd)
#pragma unroll
      for (int rr = 0; rr < 4; ++rr)
        out[(size_t)(row0 + fi * 16 + g * 4 + rr) * D_ + d0 + fd * 16 + r] =
            acc[fi][fd][rr];
}

extern "C" void kernel_launch(void* const* d_in, const int* in_sizes, int n_in,
                              void* d_out, int out_size, void* d_ws,
                              size_t ws_size, hipStream_t stream) {
  const float* M = (const float*)d_in[0];
  const int* mask = (const int*)d_in[1];
  const float* W1 = (const float*)d_in[2];
  const float* b1 = (const float*)d_in[3];
  const float* W2 = (const float*)d_in[4];
  const float* b2 = (const float*)d_in[5];
  const float* vw = (const float*)d_in[6];
  float* out = (float*)d_out;

  // workspace carve-up: 18.75 MB total
  float* w1s = (float*)d_ws;                      // [2048][128] f32   1 MB
  float* w2p = w1s + 2048 * A_;                   // [4][32][512][4]   1 MB
  ushort* ah = (ushort*)(w2p + 4 * 32 * N_ * 4);  // [2048][512] bf16  2 MB
  ushort* al = ah + 2048 * N_;                    //                   2 MB
  ushort* Mr_h = al + 2048 * N_;                  // [2048][768] bf16  3 MB
  ushort* Mr_l = Mr_h + 2048 * D_;                //                   3 MB
  ushort* Mt_h = Mr_l + 2048 * D_;                // [4][768][512]     3 MB
  ushort* Mt_l = Mt_h + 2048 * D_;                //                   3 MB
  ushort* Wt_h = Mt_l + 2048 * D_;                // [256][768] bf16   .375
  ushort* Wt_l = Wt_h + 256 * D_;                 //                   .375

  k0m<<<dim3(D_ / 64, N_ / 32, B_), 256, 0, stream>>>(M, Mr_h, Mr_l, Mt_h, Mt_l);
  k0w<<<D_ / 8, 256, 0, stream>>>(W1, W2, Wt_h, Wt_l);
  k1_mfma<<<dim3(2048 / 32, 8), 64, 0, stream>>>(Mr_h, Mr_l, Wt_h, Wt_l,
                                                 b1, b2, w1s, w2p);
  k2_scores<<<(B_ * N_) / 4, 256, 0, stream>>>(w1s, w2p, mask, vw, ah, al);
  k3_mfma<<<dim3(2048 / 32, D_ / 32), 64, 0, stream>>>(ah, al, Mt_h, Mt_l, out);
}